// Round 1
// 405.878 us; speedup vs baseline: 1.0892x; 1.0892x over previous
//
#include <hip/hip_runtime.h>
#include <hip/hip_bf16.h>

#define NODE_DIM 128
#define EDGE_DIM 32
#define HID 64
#define NEG_SLOPE 0.2f

typedef __attribute__((ext_vector_type(8))) short bf16x8;
typedef __attribute__((ext_vector_type(4))) float f32x4;

// ---------------- wave64 DPP reductions (VALU pipe, zero DS ops) ----------------

template <int CTRL, int RM, int BM>
__device__ __forceinline__ float dpp_mov(float v) {
    return __int_as_float(__builtin_amdgcn_update_dpp(
        __float_as_int(v), __float_as_int(v), CTRL, RM, BM, false));
}

__device__ __forceinline__ float wave_sum63(float v) {
    v += dpp_mov<0x111, 0xf, 0xf>(v);  // row_shr:1
    v += dpp_mov<0x112, 0xf, 0xf>(v);  // row_shr:2
    v += dpp_mov<0x114, 0xf, 0xe>(v);  // row_shr:4
    v += dpp_mov<0x118, 0xf, 0xc>(v);  // row_shr:8
    v += dpp_mov<0x142, 0xa, 0xf>(v);  // row_bcast:15
    v += dpp_mov<0x143, 0xc, 0xf>(v);  // row_bcast:31
    return v;                          // lane 63 = total
}

// sum within each 16-lane row; lane (16g+15) holds the row sum
__device__ __forceinline__ float row16_sum15(float v) {
    v += dpp_mov<0x111, 0xf, 0xf>(v);
    v += dpp_mov<0x112, 0xf, 0xf>(v);
    v += dpp_mov<0x114, 0xf, 0xe>(v);
    v += dpp_mov<0x118, 0xf, 0xc>(v);
    return v;
}

__device__ __forceinline__ float bcast63(float v) {
    return __int_as_float(__builtin_amdgcn_readlane(__float_as_int(v), 63));
}

// float -> bf16 (round to nearest even)
__device__ __forceinline__ unsigned short f2bf(float f) {
    unsigned u = __float_as_uint(f);
    unsigned r = (u + 0x7fffu + ((u >> 16) & 1u)) >> 16;
    return (unsigned short)r;
}
__device__ __forceinline__ float bf2f(unsigned short h) {
    return __uint_as_float(((unsigned)h) << 16);
}

// ---------------- CSR build ----------------

// Fused: degree count + CSR rank (atomic return value) + per-edge projections
// t1 = ea[e] . (We1@ae1), t2 = ea[e] . (We2@ae2). The 102 MB ea stream lives
// here (clean coalesced context), NOT in the scatter kernel.
__global__ void k_count_rank_t12(const int* __restrict__ col, int* __restrict__ deg,
                                 int* __restrict__ rank, const float* __restrict__ ea,
                                 const float* __restrict__ wea1,
                                 const float* __restrict__ wea2,
                                 float2* __restrict__ t12, int E) {
    int e = blockIdx.x * 256 + threadIdx.x;
    if (e >= E) return;
    rank[e] = atomicAdd(&deg[col[e]], 1);
    const float4* e4 = (const float4*)(ea + (size_t)e * EDGE_DIM);
    const float4* w1 = (const float4*)wea1;
    const float4* w2 = (const float4*)wea2;
    float t1 = 0.f, t2 = 0.f;
#pragma unroll
    for (int k = 0; k < EDGE_DIM / 4; k++) {
        float4 v = e4[k], a = w1[k], b = w2[k];
        t1 += v.x * a.x + v.y * a.y + v.z * a.z + v.w * a.w;
        t2 += v.x * b.x + v.y * b.y + v.z * b.z + v.w * b.w;
    }
    t12[e] = make_float2(t1, t2);
}

#define SCAN_B 256
__global__ void k_scan1(const int* __restrict__ deg, int* __restrict__ tmp,
                        int* __restrict__ bsum, int N) {
    __shared__ int s[SCAN_B];
    int i = blockIdx.x * SCAN_B + threadIdx.x;
    int v = (i < N) ? deg[i] : 0;
    s[threadIdx.x] = v;
    __syncthreads();
    for (int o = 1; o < SCAN_B; o <<= 1) {
        int t = (threadIdx.x >= o) ? s[threadIdx.x - o] : 0;
        __syncthreads();
        s[threadIdx.x] += t;
        __syncthreads();
    }
    if (i < N) tmp[i] = s[threadIdx.x];
    if (threadIdx.x == SCAN_B - 1) bsum[blockIdx.x] = s[threadIdx.x];
}

__global__ void k_scan2(int* __restrict__ bsum, int nb) {
    __shared__ int s[SCAN_B];
    int v = (threadIdx.x < nb) ? bsum[threadIdx.x] : 0;
    s[threadIdx.x] = v;
    __syncthreads();
    for (int o = 1; o < SCAN_B; o <<= 1) {
        int t = (threadIdx.x >= o) ? s[threadIdx.x - o] : 0;
        __syncthreads();
        s[threadIdx.x] += t;
        __syncthreads();
    }
    if (threadIdx.x < nb) bsum[threadIdx.x] = s[threadIdx.x] - v;  // exclusive
}

__global__ void k_scan3(const int* __restrict__ tmp, const int* __restrict__ deg,
                        const int* __restrict__ bsum, int* __restrict__ off, int N) {
    int i = blockIdx.x * SCAN_B + threadIdx.x;
    if (i < N) off[i] = tmp[i] - deg[i] + bsum[blockIdx.x];
}

// wea1/wea2 = We @ ae for both layers in one tiny launch (64 threads)
__global__ void k_wea2(const float* __restrict__ We1, const float* __restrict__ ae1,
                       const float* __restrict__ We2, const float* __restrict__ ae2,
                       float* __restrict__ wea1, float* __restrict__ wea2) {
    int t = threadIdx.x;
    const float* We = (t < 32) ? We1 : We2;
    const float* ae = (t < 32) ? ae1 : ae2;
    float* o = (t < 32) ? wea1 : wea2;
    int k = t & 31;
    float s = 0.f;
#pragma unroll
    for (int j = 0; j < HID; j++) s += We[k * HID + j] * ae[j];
    o[k] = s;
}

// CSR fill: pure scatter, NO atomics (rank precomputed in k_count_rank_t12),
// NO ea stream (t12 precomputed, coalesced 8B read). Single 16B scatter/edge:
// pk[p] = (t1, t2, src, t1 + ss1[src])  -- .w pre-folds layer-1's s_src gather.
__global__ void k_fill_pack(const int* __restrict__ row, const int* __restrict__ col,
                            const int* __restrict__ off, const int* __restrict__ rank,
                            const float2* __restrict__ t12, const float* __restrict__ ss1,
                            float4* __restrict__ pk, int E) {
    int e = blockIdx.x * 256 + threadIdx.x;
    if (e >= E) return;
    int dn = col[e];
    int p = off[dn] + rank[e];
    float2 t = t12[e];
    int sr = row[e];
    pk[p] = make_float4(t.x, t.y, __int_as_float(sr), t.x + ss1[sr]);
}

// ---------------- node GEMMs via split-bf16 MFMA ----------------
// H[N x (16*NT)] = X[N x K] @ W, W row-stride 64. Split x = hi+lo, W = hi+lo;
// 3 MFMAs (hi*hi + hi*lo + lo*hi) give ~16 mantissa bits (f32-quality).
// OUTPUT IS bf16 (gather rows downstream are 128 B, not 256 B).
// s_src/s_dst computed from f32 accumulators (exact).
template <int K, int NT, bool ATT, bool PQ>
__global__ __launch_bounds__(256) void k_gemm_mfma(
    const float* __restrict__ X, const float* __restrict__ W,
    const float* __restrict__ as_, const float* __restrict__ ad_,
    unsigned short* __restrict__ H, unsigned short* __restrict__ H2,
    float* __restrict__ ss, float* __restrict__ sd, int N) {
    constexpr int KC = K / 32;
    int wv = threadIdx.x >> 6, lane = threadIdx.x & 63;
    int g = lane >> 4, li = lane & 15;
    bf16x8 bhi[KC][NT], blo[KC][NT];
#pragma unroll
    for (int c = 0; c < KC; c++)
#pragma unroll
        for (int t = 0; t < NT; t++)
#pragma unroll
            for (int j = 0; j < 8; j++) {
                int k = 32 * c + 8 * g + j;
                size_t idx = (size_t)(k + ((PQ && t >= 4) ? HID : 0)) * HID + 16 * (t & 3) + li;
                float w = W[idx];
                unsigned short h = f2bf(w);
                bhi[c][t][j] = (short)h;
                blo[c][t][j] = (short)f2bf(w - bf2f(h));
            }
    float asl[NT], adl[NT];
    if (ATT) {
#pragma unroll
        for (int t = 0; t < NT; t++) {
            asl[t] = as_[16 * t + li];
            adl[t] = ad_[16 * t + li];
        }
    }
    int ntile = (N + 15) >> 4;
    for (int tb = blockIdx.x * 4 + wv; tb < ntile; tb += gridDim.x * 4) {
        int node = tb * 16 + li;
        if (node >= N) node = N - 1;
        const float* xrow = X + (size_t)node * K;
        bf16x8 ahi[KC], alo[KC];
#pragma unroll
        for (int c = 0; c < KC; c++) {
            float4 a0 = *(const float4*)(xrow + 32 * c + 8 * g);
            float4 a1 = *(const float4*)(xrow + 32 * c + 8 * g + 4);
            float xv[8] = {a0.x, a0.y, a0.z, a0.w, a1.x, a1.y, a1.z, a1.w};
#pragma unroll
            for (int j = 0; j < 8; j++) {
                unsigned short h = f2bf(xv[j]);
                ahi[c][j] = (short)h;
                alo[c][j] = (short)f2bf(xv[j] - bf2f(h));
            }
        }
        f32x4 acc[NT];
#pragma unroll
        for (int t = 0; t < NT; t++) acc[t] = (f32x4){0.f, 0.f, 0.f, 0.f};
#pragma unroll
        for (int c = 0; c < KC; c++) {
#pragma unroll
            for (int t = 0; t < NT; t++)
                acc[t] = __builtin_amdgcn_mfma_f32_16x16x32_bf16(ahi[c], bhi[c][t], acc[t], 0, 0, 0);
#pragma unroll
            for (int t = 0; t < NT; t++)
                acc[t] = __builtin_amdgcn_mfma_f32_16x16x32_bf16(ahi[c], blo[c][t], acc[t], 0, 0, 0);
#pragma unroll
            for (int t = 0; t < NT; t++)
                acc[t] = __builtin_amdgcn_mfma_f32_16x16x32_bf16(alo[c], bhi[c][t], acc[t], 0, 0, 0);
        }
        int nbase = tb * 16 + 4 * g;
#pragma unroll
        for (int t = 0; t < NT; t++) {
            unsigned short* dst = (PQ && t >= 4) ? H2 : H;
            int cofs = 16 * (t & 3) + li;
#pragma unroll
            for (int r = 0; r < 4; r++) {
                int n = nbase + r;
                if (n < N) dst[(size_t)n * HID + cofs] = f2bf(acc[t][r]);
            }
        }
        if (ATT) {
#pragma unroll
            for (int r = 0; r < 4; r++) {
                float s1 = 0.f, s2 = 0.f;
#pragma unroll
                for (int t = 0; t < NT; t++) {
                    s1 += acc[t][r] * asl[t];
                    s2 += acc[t][r] * adl[t];
                }
                s1 = row16_sum15(s1);
                s2 = row16_sum15(s2);
                int n = nbase + r;
                if (li == 15 && n < N) {
                    ss[n] = s1;
                    sd[n] = s2;
                }
            }
        }
    }
}

// ---------------- GAT aggregation (single pass, no max subtraction) ----------------
// H rows are bf16 (128 B gathers). FOLD (layer 1): logit base pre-folded in
// pk.w. !FOLD (layer 2): gather ss[src].
template <bool FOLD>
__global__ __launch_bounds__(256) void k_aggregate(
    const unsigned short* __restrict__ H, const float* __restrict__ ss,
    const float* __restrict__ sd, const float4* __restrict__ pk,
    const int* __restrict__ off, const int* __restrict__ deg,
    const float* __restrict__ b, float* __restrict__ Xo, int N) {
    __shared__ __align__(16) float2 sh[4][64];
    int wv = threadIdx.x >> 6, lane = threadIdx.x & 63;
    int n = blockIdx.x * 4 + wv;
    if (n >= N) return;
    int st = off[n], d = deg[n];
    float sdn = sd[n];
    float tsum = 0.f, dsum = 0.f, acc = 0.f;
    for (int base = 0; base < d; base += 64) {
        int i = base + lane;
        float w = 0.f;
        int s = 0;
        if (i < d) {
            float4 p = pk[st + i];
            s = __float_as_int(p.z);
            float z;
            if (FOLD) {
                tsum += p.x;
                z = p.w + sdn;
            } else {
                tsum += p.y;
                z = ss[s] + sdn + p.y;
            }
            float l = z > 0.f ? z : NEG_SLOPE * z;
            w = __expf(l);
            dsum += w;
        }
        sh[wv][lane] = make_float2(w, __int_as_float(s));
        int cnt = d - base;
        if (cnt > 64) cnt = 64;
        int j = 0;
        for (; j + 4 <= cnt; j += 4) {
            float4 a0 = *(const float4*)&sh[wv][j];
            float4 a1 = *(const float4*)&sh[wv][j + 2];
            float h0 = bf2f(H[(size_t)__float_as_int(a0.y) * HID + lane]);
            float h1 = bf2f(H[(size_t)__float_as_int(a0.w) * HID + lane]);
            float h2 = bf2f(H[(size_t)__float_as_int(a1.y) * HID + lane]);
            float h3 = bf2f(H[(size_t)__float_as_int(a1.w) * HID + lane]);
            acc += a0.x * h0 + a0.z * h1 + a1.x * h2 + a1.z * h3;
        }
        for (; j < cnt; j++) {
            float2 pr = sh[wv][j];
            acc += pr.x * bf2f(H[(size_t)__float_as_int(pr.y) * HID + lane]);
        }
    }
    tsum = bcast63(wave_sum63(tsum));
    dsum = bcast63(wave_sum63(dsum));
    float tloop = tsum / (float)(d > 1 ? d : 1);
    float zs = ss[n] + sdn + tloop;
    float lself = zs > 0.f ? zs : NEG_SLOPE * zs;
    float wself = __expf(lself);
    acc += wself * bf2f(H[(size_t)n * HID + lane]);
    dsum += wself;
    float v = acc / dsum + b[lane];
    Xo[(size_t)n * HID + lane] = fmaxf(v, 0.f);  // relu fused
}

// ---------------- edge classifier via MFMA (P/Q rows bf16, 128 B gathers) ----------------
__global__ __launch_bounds__(256) void k_edge_final_mfma(
    const unsigned short* __restrict__ P, const unsigned short* __restrict__ Q,
    const float* __restrict__ ea, const int* __restrict__ row,
    const int* __restrict__ col, const float* __restrict__ Wc1,
    const float* __restrict__ bc1, const float* __restrict__ Wc2,
    const float* __restrict__ bc2, float* __restrict__ out, int E) {
    int wv = threadIdx.x >> 6, lane = threadIdx.x & 63;
    int g = lane >> 4, li = lane & 15;
    bf16x8 bfrag[4];
#pragma unroll
    for (int t = 0; t < 4; t++) {
#pragma unroll
        for (int j = 0; j < 8; j++)
            bfrag[t][j] = (short)f2bf(Wc1[(size_t)(2 * HID + 8 * g + j) * HID + 16 * t + li]);
    }
    float bcv[4], wc2v[4];
#pragma unroll
    for (int t = 0; t < 4; t++) {
        bcv[t] = bc1[16 * t + li];
        wc2v[t] = Wc2[16 * t + li];
    }
    float bc2v = bc2[0];
    int ntile = (E + 15) >> 4;
    for (int tb = blockIdx.x * 4 + wv; tb < ntile; tb += gridDim.x * 4) {
        int eb = tb << 4;
        int ae_e = eb + li;
        if (ae_e >= E) ae_e = E - 1;
        const float4* ap = (const float4*)(ea + (size_t)ae_e * EDGE_DIM + 8 * g);
        float4 a0 = ap[0], a1 = ap[1];
        bf16x8 afrag;
        afrag[0] = (short)f2bf(a0.x); afrag[1] = (short)f2bf(a0.y);
        afrag[2] = (short)f2bf(a0.z); afrag[3] = (short)f2bf(a0.w);
        afrag[4] = (short)f2bf(a1.x); afrag[5] = (short)f2bf(a1.y);
        afrag[6] = (short)f2bf(a1.z); afrag[7] = (short)f2bf(a1.w);
        f32x4 acc[4];
#pragma unroll
        for (int t = 0; t < 4; t++) {
            f32x4 z = {0.f, 0.f, 0.f, 0.f};
            acc[t] = __builtin_amdgcn_mfma_f32_16x16x32_bf16(afrag, bfrag[t], z, 0, 0, 0);
        }
        int e0 = eb + 4 * g;
        int rr[4], cc[4];
        if (e0 + 3 < E) {
            int4 rv = *(const int4*)(row + e0);
            int4 cv = *(const int4*)(col + e0);
            rr[0] = rv.x; rr[1] = rv.y; rr[2] = rv.z; rr[3] = rv.w;
            cc[0] = cv.x; cc[1] = cv.y; cc[2] = cv.z; cc[3] = cv.w;
        } else {
            for (int r = 0; r < 4; r++) {
                int e = e0 + r; if (e >= E) e = E - 1;
                rr[r] = row[e]; cc[r] = col[e];
            }
        }
        float pe[4];
#pragma unroll
        for (int r = 0; r < 4; r++) {
            const unsigned short* pr = P + (size_t)rr[r] * HID;
            const unsigned short* qr = Q + (size_t)cc[r] * HID;
            float s = 0.f;
#pragma unroll
            for (int t = 0; t < 4; t++) {
                float h = acc[t][r] + bf2f(pr[16 * t + li]) + bf2f(qr[16 * t + li]) + bcv[t];
                h = fmaxf(h, 0.f);
                s += h * wc2v[t];
            }
            pe[r] = s;
        }
#pragma unroll
        for (int r = 0; r < 4; r++) pe[r] = row16_sum15(pe[r]);
        if (li == 15) {
            if (e0 + 3 < E) {
                *(float4*)(out + e0) =
                    make_float4(pe[0] + bc2v, pe[1] + bc2v, pe[2] + bc2v, pe[3] + bc2v);
            } else {
                for (int r = 0; r < 4; r++)
                    if (e0 + r < E) out[e0 + r] = pe[r] + bc2v;
            }
        }
    }
}

// ---------------- launch ----------------

extern "C" void kernel_launch(void* const* d_in, const int* in_sizes, int n_in,
                              void* d_out, int out_size, void* d_ws, size_t ws_size,
                              hipStream_t stream) {
    const float* x = (const float*)d_in[0];
    const int* eidx = (const int*)d_in[1];
    const float* ea = (const float*)d_in[2];
    const float* W1 = (const float*)d_in[3];
    const float* We1 = (const float*)d_in[4];
    const float* as1 = (const float*)d_in[5];
    const float* ad1 = (const float*)d_in[6];
    const float* ae1 = (const float*)d_in[7];
    const float* b1 = (const float*)d_in[8];
    const float* W2 = (const float*)d_in[9];
    const float* We2 = (const float*)d_in[10];
    const float* as2 = (const float*)d_in[11];
    const float* ad2 = (const float*)d_in[12];
    const float* ae2 = (const float*)d_in[13];
    const float* b2 = (const float*)d_in[14];
    const float* Wc1 = (const float*)d_in[15];
    const float* bc1 = (const float*)d_in[16];
    const float* Wc2 = (const float*)d_in[17];
    const float* bc2 = (const float*)d_in[18];
    float* out = (float*)d_out;

    const int N = in_sizes[0] / NODE_DIM;
    const int E = in_sizes[1] / 2;
    const int* row = eidx;
    const int* col = eidx + E;

    char* ws = (char*)d_ws;
    size_t o = 0;
    auto carve = [&](size_t bytes) -> char* {
        char* p = ws + o;
        o += (bytes + 255) & ~(size_t)255;
        return p;
    };
    int* deg = (int*)carve((size_t)N * 4);
    int* off = (int*)carve((size_t)N * 4);
    int* tmp = (int*)carve((size_t)N * 4);
    int* bsum = (int*)carve(SCAN_B * 4);
    int* rank = (int*)carve((size_t)E * 4);          // CSR rank per edge (from count atomic)
    float2* t12 = (float2*)carve((size_t)E * 8);     // per-edge (t1, t2) projections
    float4* pk12 = (float4*)carve((size_t)E * 16);
    float* wea1 = (float*)carve(EDGE_DIM * 4);
    float* wea2 = (float*)carve(EDGE_DIM * 4);
    float* ssrc = (float*)carve((size_t)N * 4);
    float* sdst = (float*)carve((size_t)N * 4);
    unsigned short* hbuf = (unsigned short*)carve((size_t)N * HID * 2);   // H (bf16), later Q
    unsigned short* pbuf = (unsigned short*)carve((size_t)N * HID * 2);   // P (bf16)
    float* x1 = (float*)carve((size_t)N * HID * 4);
    float* x2 = (float*)carve((size_t)N * HID * 4);
    (void)ws_size;

    const int gE = (E + 255) / 256;
    const int gN256 = (N + SCAN_B - 1) / SCAN_B;
    const int gN4 = (N + 3) / 4;
    const int gT = ((N + 15) / 16 + 3) / 4;  // wave-per-16-node-tile blocks

    // CSR offsets + per-edge projections
    (void)hipMemsetAsync(deg, 0, (size_t)N * 4, stream);
    k_wea2<<<1, 64, 0, stream>>>(We1, ae1, We2, ae2, wea1, wea2);
    k_count_rank_t12<<<gE, 256, 0, stream>>>(col, deg, rank, ea, wea1, wea2, t12, E);
    k_scan1<<<gN256, SCAN_B, 0, stream>>>(deg, tmp, bsum, N);
    k_scan2<<<1, SCAN_B, 0, stream>>>(bsum, gN256);
    k_scan3<<<gN256, SCAN_B, 0, stream>>>(tmp, deg, bsum, off, N);

    // layer-1 GEMM first so fill_pack can fold ss1[src] into the record
    k_gemm_mfma<NODE_DIM, 4, true, false><<<gT, 256, 0, stream>>>(
        x, W1, as1, ad1, hbuf, nullptr, ssrc, sdst, N);
    k_fill_pack<<<gE, 256, 0, stream>>>(row, col, off, rank, t12, ssrc, pk12, E);

    // layer 1 aggregate
    k_aggregate<true><<<gN4, 256, 0, stream>>>(hbuf, ssrc, sdst, pk12, off, deg, b1, x1, N);

    // layer 2
    k_gemm_mfma<HID, 4, true, false><<<gT, 256, 0, stream>>>(
        x1, W2, as2, ad2, hbuf, nullptr, ssrc, sdst, N);
    k_aggregate<false><<<gN4, 256, 0, stream>>>(hbuf, ssrc, sdst, pk12, off, deg, b2, x2, N);

    // classifier: P/Q fused GEMM (bf16 out) then edge MLP
    k_gemm_mfma<HID, 8, false, true><<<gT, 256, 0, stream>>>(
        x2, Wc1, nullptr, nullptr, pbuf, hbuf, nullptr, nullptr, N);
    k_edge_final_mfma<<<2048, 256, 0, stream>>>(pbuf, hbuf, ea, row, col, Wc1, bc1, Wc2, bc2, out, E);
}